// Round 3
// baseline (169.876 us; speedup 1.0000x reference)
//
#include <hip/hip_runtime.h>
#include <math.h>

#define HW2   62
#define NANCH 34596   // 62*62*9
#define NBAT  16
#define NGT   8
#define FEATC 256
#define NOUT  45      // 9 cls + 36 box channels

typedef short bf16x8 __attribute__((ext_vector_type(8)));
typedef float f32x4  __attribute__((ext_vector_type(4)));

// fp32 -> bf16 round-to-nearest-even
__device__ __forceinline__ unsigned short f2bf(float f) {
    unsigned int u = __float_as_uint(f);
    u = u + 0x7FFFu + ((u >> 16) & 1u);
    return (unsigned short)(u >> 16);
}

// ---------- shared device helpers (bitwise identical to passing R2) ----------

__device__ __forceinline__ void anchor4(int i, int j, int a,
                                        float& x1, float& y1, float& x2, float& y2) {
    int am = a % 3, ad = a / 3;
    float h = 2.f * (float)(am + 1);              // 2,4,6
    float w = h * 0.5f * (float)(1 << ad);        // h*{0.5,1,2}
    float cx = (float)i + 0.5f, cy = (float)j + 0.5f;
    x1 = fminf(fmaxf(cx - 0.5f * w, 0.f), 62.f);
    x2 = fminf(fmaxf(cx + 0.5f * w, 0.f), 62.f);
    y1 = fminf(fmaxf(cy - 0.5f * h, 0.f), 62.f);
    y2 = fminf(fmaxf(cy + 0.5f * h, 0.f), 62.f);
}

__device__ __forceinline__ float iou_fn(float ax1, float ay1, float ax2, float ay2,
                                        float gx1, float gy1, float gx2, float gy2) {
    float area_a = __fmul_rn(__fsub_rn(ax2, ax1), __fsub_rn(ay2, ay1));
    float area_g = __fmul_rn(__fsub_rn(gx2, gx1), __fsub_rn(gy2, gy1));
    float ix1 = fmaxf(ax1, gx1), iy1 = fmaxf(ay1, gy1);
    float ix2 = fminf(ax2, gx2), iy2 = fminf(ay2, gy2);
    float iw = fmaxf(__fsub_rn(ix2, ix1), 0.f);
    float ih = fmaxf(__fsub_rn(iy2, iy1), 0.f);
    float inter = __fmul_rn(iw, ih);
    float uni = __fsub_rn(__fadd_rn(area_a, area_g), inter);
    return inter / fmaxf(uni, 1e-9f);
}

__device__ __forceinline__ float softplus_f(float x) {
    return fmaxf(x, 0.f) + log1pf(expf(-fabsf(x)));
}

__device__ __forceinline__ float sl1_f(float d) {
    float ad = fabsf(d);
    return (ad < 1.f) ? 0.5f * d * d : (ad - 0.5f);
}

// ---------- Kernel 1: fold partials, head weights staged in LDS ----------
// grid (9, 4): 256 idx per block, 64 mids per group
// partial[(g*45+o)*2304 + idx]  (coalesced stores)
__global__ void fold_part(const float* __restrict__ conv_w,
                          const float* __restrict__ cls_w,
                          const float* __restrict__ box_w,
                          float* __restrict__ partial,
                          unsigned int* __restrict__ counter) {
    if (blockIdx.x == 0 && blockIdx.y == 0 && threadIdx.x == 0) *counter = 0u;
    __shared__ float w2s[64][45];
    int g = blockIdx.y, t = threadIdx.x;
    for (int i = t; i < 64 * 45; i += 256) {
        int m = i / 45, o = i - m * 45;
        w2s[m][o] = (o < 9) ? cls_w[o * FEATC + g * 64 + m]
                            : box_w[(o - 9) * FEATC + g * 64 + m];
    }
    __syncthreads();
    int idx = blockIdx.x * 256 + t;
    float acc[NOUT];
#pragma unroll
    for (int o = 0; o < NOUT; ++o) acc[o] = 0.f;
    for (int m = 0; m < 64; ++m) {
        float cw = conv_w[(size_t)(g * 64 + m) * 2304 + idx];   // coalesced
#pragma unroll
        for (int o = 0; o < NOUT; ++o)
            acc[o] = fmaf(cw, w2s[m][o], acc[o]);               // LDS broadcast
    }
#pragma unroll
    for (int o = 0; o < NOUT; ++o)
        partial[(size_t)(g * NOUT + o) * 2304 + idx] = acc[o];  // coalesced
}

// ---------- Kernel 2: combine -> Bfrag (bf16) | gt max-iou | effb ----------
// blocks [0,432): combine; [432,560): gtmax; [560]: effb
__global__ void prep2(const float* __restrict__ partial,
                      const float* __restrict__ conv_b,
                      const float* __restrict__ cls_b,
                      const float* __restrict__ box_b,
                      const float* __restrict__ cls_w,
                      const float* __restrict__ box_w,
                      const float* __restrict__ gtb,
                      unsigned short* __restrict__ Bfrag,
                      float* __restrict__ effb,
                      float* __restrict__ maxiou) {
    __shared__ float red[256];
    int blk = blockIdx.x, t = threadIdx.x;
    if (blk < 432) {
        int i = blk * 256 + t;               // < 110592 = 48*2304
        int o = i / 2304, idx = i - o * 2304;
        float s = 0.f;
        if (o < NOUT) {
#pragma unroll
            for (int g = 0; g < 4; ++g)
                s += partial[(size_t)(g * NOUT + o) * 2304 + idx];  // coalesced
        }
        int c = idx / 9, tap = idx - c * 9;
        int cc = c >> 6, kk = (c >> 5) & 1, lh = (c >> 3) & 3, j = c & 7;
        int lane = (lh << 4) | (o & 15), nf = o >> 4;
        Bfrag[((size_t)((((cc * 9 + tap) * 2 + kk) * 3 + nf) * 64 + lane)) * 8 + j] = f2bf(s);
    } else if (blk < 560) {
        int bg = blk - 432;
        int b = bg >> 3, g = bg & 7;
        const float* p = gtb + (b * NGT + g) * 4;
        float gx1 = p[0] * 0.125f, gy1 = p[1] * 0.125f;
        float gx2 = p[2] * 0.125f, gy2 = p[3] * 0.125f;
        float m = 0.f;
        for (int n = t; n < NANCH; n += 256) {
            int i = n / 558; int r = n - i * 558; int j = r / 9; int a = r - j * 9;
            float ax1, ay1, ax2, ay2;
            anchor4(i, j, a, ax1, ay1, ax2, ay2);
            m = fmaxf(m, iou_fn(ax1, ay1, ax2, ay2, gx1, gy1, gx2, gy2));
        }
        red[t] = m;
        __syncthreads();
        for (int s = 128; s > 0; s >>= 1) {
            if (t < s) red[t] = fmaxf(red[t], red[t + s]);
            __syncthreads();
        }
        if (t == 0) maxiou[bg] = red[0];
    } else {
        if (t < 48) {
            float bv = 0.f;
            if (t < NOUT) {
                bv = (t < 9) ? cls_b[t] : box_b[t - 9];
                const float* w2 = (t < 9) ? (cls_w + t * FEATC) : (box_w + (t - 9) * FEATC);
                for (int mid = 0; mid < FEATC; ++mid) bv = fmaf(w2[mid], conv_b[mid], bv);
            }
            effb[t] = bv;
        }
    }
}

// ---------- Kernel 3: MFMA conv + fused epilogue + fused finalize ----------
// grid = (32 spatial tiles [8 tY x 4 tX], 16 batch), block = 256 (4 waves)
// Single LDS A-buffer (reg prefetch across the sync), Cs overlaid on it.
__launch_bounds__(256, 4)
__global__ void conv_fused(const float* __restrict__ feat,
                           const unsigned short* __restrict__ Bfrag,
                           const float* __restrict__ effb,
                           const float* __restrict__ gtb,
                           const int* __restrict__ gtc,
                           const float* __restrict__ maxiou,
                           float* __restrict__ outp,
                           float* __restrict__ blksums,
                           unsigned int* __restrict__ counter) {
    __shared__ __align__(16) unsigned char smem[25600];  // union: A-tile 23040B | Cs 128*49*4B
    __shared__ float gshr[40];
    __shared__ float red[256];
    __shared__ float tot[5];
    __shared__ unsigned int lastflag;

    float (*Cs)[49] = (float (*)[49])smem;

    const int t = threadIdx.x, l = t & 63, w = t >> 6;
    const int bx = blockIdx.x, b = blockIdx.y;
    const int tY = bx >> 2, tX = bx & 3;
    const int l15 = l & 15, lq = l >> 4;

    if (t < 32) gshr[t] = gtb[b * 32 + t] * 0.125f;
    else if (t < 40) gshr[t] = maxiou[b * 8 + (t - 32)];

    f32x4 acc[2][3];
#pragma unroll
    for (int nf = 0; nf < 3; ++nf) {
        float bv = effb[nf * 16 + l15];
#pragma unroll
        for (int mf = 0; mf < 2; ++mf)
#pragma unroll
            for (int r = 0; r < 4; ++r) acc[mf][nf][r] = bv;
    }

    float vr[6][8];  // raw fp32 prefetch regs (held across compute)

    auto stage_load = [&](int cc) {
#pragma unroll
        for (int q = 0; q < 6; ++q) {
            int pi = w * 6 + q;                 // 0..23
            int pg = pi >> 3, cg = pi & 7;
            int pix = pg * 64 + l;              // 0..191 (need <180)
            int iy = pix / 18, ix = pix - iy * 18;
            int gy = tY * 8 + iy, gx = tX * 16 + ix;
            bool ok = (pix < 180) && (gy < 64) && (gx < 64);
            const float* src = feat + (((size_t)b * FEATC + cc * 64 + cg * 8) * 64 + gy) * 64 + gx;
#pragma unroll
            for (int k = 0; k < 8; ++k)
                vr[q][k] = ok ? src[(size_t)k * 4096] : 0.f;
        }
    };
    auto stage_write = [&]() {
        char* base = (char*)smem;
#pragma unroll
        for (int q = 0; q < 6; ++q) {
            int pi = w * 6 + q;
            int pg = pi >> 3, cg = pi & 7;
            int pix = pg * 64 + l;
            if (pix < 180) {
                bf16x8 v;
#pragma unroll
                for (int k = 0; k < 8; ++k) v[k] = (short)f2bf(vr[q][k]);
                int byte = (pix * 128 + cg * 16) ^ ((pix & 7) << 4);
                *reinterpret_cast<bf16x8*>(base + byte) = v;
            }
        }
    };
    auto compute = [&](int cc) {
        const bf16x8* Bp = reinterpret_cast<const bf16x8*>(Bfrag);
        const char* base = (const char*)smem;
#pragma unroll
        for (int dy = 0; dy < 3; ++dy)
#pragma unroll
            for (int dx = 0; dx < 3; ++dx)
#pragma unroll
                for (int kk = 0; kk < 2; ++kk) {
                    int tap = dy * 3 + dx;
                    bf16x8 bfr[3];
#pragma unroll
                    for (int nf = 0; nf < 3; ++nf)
                        bfr[nf] = Bp[(((cc * 9 + tap) * 2 + kk) * 3 + nf) * 64 + l];
                    bf16x8 afr[2];
#pragma unroll
                    for (int mf = 0; mf < 2; ++mf) {
                        int pix = (w * 2 + mf + dy) * 18 + l15 + dx;
                        int byte = (pix * 128 + kk * 64 + (lq << 4)) ^ ((pix & 7) << 4);
                        afr[mf] = *reinterpret_cast<const bf16x8*>(base + byte);
                    }
#pragma unroll
                    for (int mf = 0; mf < 2; ++mf)
#pragma unroll
                        for (int nf = 0; nf < 3; ++nf)
                            acc[mf][nf] = __builtin_amdgcn_mfma_f32_16x16x32_bf16(
                                afr[mf], bfr[nf], acc[mf][nf], 0, 0, 0);
                }
    };

    // K-loop, single LDS buffer; prefetch for cc+1 rides in regs across compute(cc)
    stage_load(0);
    stage_write();
    __syncthreads();
    for (int cc = 0; cc < 4; ++cc) {
        if (cc < 3) stage_load(cc + 1);   // issue loads; values consumed after the sync
        compute(cc);
        __syncthreads();                  // all waves done reading A
        if (cc < 3) {
            stage_write();                // overwrite the single buffer
            __syncthreads();
        }
    }

    // C fragments -> LDS (Cs overlays A; safe after the trailing sync)
#pragma unroll
    for (int mf = 0; mf < 2; ++mf) {
        int py = w * 2 + mf;
#pragma unroll
        for (int nf = 0; nf < 3; ++nf)
#pragma unroll
            for (int r = 0; r < 4; ++r) {
                int px = (lq << 2) + r;
                Cs[py * 16 + px][nf * 16 + l15] = acc[mf][nf][r];
            }
    }
    __syncthreads();

    // ---- fused per-anchor epilogue: 8x16 pixels x 9 anchors = 1152 anchors ----
    float s_pos = 0.f, s_neg = 0.f, s_pl = 0.f, s_nl = 0.f, s_reg = 0.f;
    float* out_prop = outp + 2;
    float* out_mask = out_prop + (size_t)NBAT * NANCH * 4;
    float* out_gtc  = out_mask + (size_t)NBAT * NANCH * 8;

    for (int k = 0; k < 5; ++k) {
        int an = k * 256 + t;
        if (an < 1152) {
            int pixloc = an / 9, a = an - pixloc * 9;
            int py = pixloc >> 4, px = pixloc & 15;
            int oy = tY * 8 + py, ox = tX * 16 + px;
            if (oy < HW2 && ox < HW2) {
                int n = oy * 558 + ox * 9 + a;
                float cls = Cs[pixloc][a];
                float p0 = Cs[pixloc][9 + 4 * a];
                float p1 = Cs[pixloc][10 + 4 * a];
                float p2 = Cs[pixloc][11 + 4 * a];
                float p3 = Cs[pixloc][12 + 4 * a];

                float ax1, ay1, ax2, ay2;
                anchor4(oy, ox, a, ax1, ay1, ax2, ay2);
                float aw = ax2 - ax1, ah = ay2 - ay1;
                float acx = 0.5f * (ax1 + ax2), acy = 0.5f * (ay1 + ay2);

                const float ps = 64.f / 62.f;
                float pcx = acx + p0 * aw, pcy = acy + p1 * ah;
                float pw = aw * expf(p2), ph = ah * expf(p3);
                size_t pb = ((size_t)b * NANCH + n) * 4;
                out_prop[pb + 0] = (pcx - 0.5f * pw) * ps;
                out_prop[pb + 1] = (pcy - 0.5f * ph) * ps;
                out_prop[pb + 2] = (pcx + 0.5f * pw) * ps;
                out_prop[pb + 3] = (pcy + 0.5f * ph) * ps;

                float law = logf(aw), lah = logf(ah);
                float posf_tot = 0.f, negf_tot = 0.f;
                float best_iou = -1.f; int best_g = 0;
                size_t mb = ((size_t)b * NANCH + n) * 8;
#pragma unroll
                for (int g = 0; g < NGT; ++g) {
                    float gx1 = gshr[g * 4 + 0], gy1 = gshr[g * 4 + 1];
                    float gx2 = gshr[g * 4 + 2], gy2 = gshr[g * 4 + 3];
                    float iou = iou_fn(ax1, ay1, ax2, ay2, gx1, gy1, gx2, gy2);
                    float mpg = gshr[32 + g];
                    bool pm = ((iou == mpg) && (mpg > 0.f)) || (iou > 0.7f);
                    float pf = pm ? 1.f : 0.f;
                    float nf = (iou < 0.3f) ? 1.f : 0.f;
                    out_mask[mb + g] = pf;
                    posf_tot += pf; negf_tot += nf;
                    if (iou > best_iou) { best_iou = iou; best_g = g; }  // first-max-wins
                    if (pm) {
                        float gw = gx2 - gx1, gh = gy2 - gy1;
                        float gcx = 0.5f * (gx1 + gx2), gcy = 0.5f * (gy1 + gy2);
                        float tx_ = (gcx - acx) / aw, ty_ = (gcy - acy) / ah;
                        float tw_ = logf(gw) - law, th_ = logf(gh) - lah;
                        float d0 = p0 - tx_, d1 = p1 - ty_, d2 = p2 - tw_, d3 = p3 - th_;
                        s_reg += sl1_f(d0) + sl1_f(d1) + sl1_f(d2) + sl1_f(d3);
                    }
                }
                s_pos += posf_tot; s_neg += negf_tot;
                s_pl += softplus_f(-cls) * posf_tot;
                s_nl += softplus_f(cls) * negf_tot;
                out_gtc[(size_t)b * NANCH + n] = (float)gtc[b * NGT + best_g];
            }
        }
    }

    // deterministic per-block tree reduction of the 5 loss partials
    int blk = b * 32 + bx;   // nblk = 512
    float vals[5] = {s_pos, s_neg, s_pl, s_nl, s_reg};
#pragma unroll
    for (int s = 0; s < 5; ++s) {
        red[t] = vals[s];
        __syncthreads();
        for (int st = 128; st > 0; st >>= 1) {
            if (t < st) red[t] += red[t + st];
            __syncthreads();
        }
        if (t == 0) blksums[(size_t)s * 512 + blk] = red[0];
        __syncthreads();
    }

    // fused finalize: last block (fence+atomic) does the fixed-order reduce
    if (t == 0) {
        __threadfence();
        lastflag = (atomicAdd(counter, 1u) == 511u) ? 1u : 0u;
    }
    __syncthreads();
    if (lastflag) {
        __threadfence();
#pragma unroll
        for (int s = 0; s < 5; ++s) {
            float a = 0.f;
            for (int i = t; i < 512; i += 256) a += blksums[(size_t)s * 512 + i];
            red[t] = a;
            __syncthreads();
            for (int st = 128; st > 0; st >>= 1) {
                if (t < st) red[t] += red[t + st];
                __syncthreads();
            }
            if (t == 0) tot[s] = red[0];
            __syncthreads();
        }
        if (t == 0) {
            float np_ = fmaxf(tot[0], 1.f), nn_ = fmaxf(tot[1], 1.f);
            outp[0] = 0.5f * (tot[2] / np_ + tot[3] / nn_);  // cls_loss
            outp[1] = tot[4] / (np_ * 4.f);                  // reg_loss
        }
    }
}

extern "C" void kernel_launch(void* const* d_in, const int* in_sizes, int n_in,
                              void* d_out, int out_size, void* d_ws, size_t ws_size,
                              hipStream_t stream) {
    (void)in_sizes; (void)n_in; (void)out_size; (void)ws_size;
    const float* feat   = (const float*)d_in[0];
    const float* gtb    = (const float*)d_in[1];
    const int*   gtc    = (const int*)d_in[2];
    const float* conv_w = (const float*)d_in[3];
    const float* conv_b = (const float*)d_in[4];
    const float* cls_w  = (const float*)d_in[5];
    const float* cls_b  = (const float*)d_in[6];
    const float* box_w  = (const float*)d_in[7];
    const float* box_b  = (const float*)d_in[8];
    float* outp = (float*)d_out;
    float* ws   = (float*)d_ws;

    // workspace layout (floats), ~1.85 MB total
    unsigned short* Bfrag   = (unsigned short*)ws;            // 110592 ushorts = 55296 fl
    float*          effb    = ws + 55296;                     // 48 (pad to 64)
    float*          maxiou  = ws + 55360;                     // 128
    unsigned int*   counter = (unsigned int*)(ws + 55488);    // 1 (pad to 64)
    float*          partial = ws + 55552;                     // 4*45*2304 = 414720
    float*          blksums = ws + 470272;                    // 5*512

    fold_part<<<dim3(9, 4), 256, 0, stream>>>(conv_w, cls_w, box_w, partial, counter);
    prep2<<<561, 256, 0, stream>>>(partial, conv_b, cls_b, box_b, cls_w, box_w, gtb,
                                   Bfrag, effb, maxiou);
    conv_fused<<<dim3(32, NBAT), 256, 0, stream>>>(feat, Bfrag, effb, gtb, gtc, maxiou,
                                                   outp, blksums, counter);
}

// Round 4
// 118.138 us; speedup vs baseline: 1.4379x; 1.4379x over previous
//
#include <hip/hip_runtime.h>
#include <math.h>

#define HW2   62
#define NANCH 34596   // 62*62*9
#define NBAT  16
#define NGT   8
#define FEATC 256
#define NOUT  45      // 9 cls + 36 box channels

typedef short bf16x8 __attribute__((ext_vector_type(8)));
typedef float f32x4  __attribute__((ext_vector_type(4)));

// fp32 -> bf16 round-to-nearest-even
__device__ __forceinline__ unsigned short f2bf(float f) {
    unsigned int u = __float_as_uint(f);
    u = u + 0x7FFFu + ((u >> 16) & 1u);
    return (unsigned short)(u >> 16);
}

// ---------- shared device helpers (bitwise identical to passing R2/R3) ----------

__device__ __forceinline__ void anchor4(int i, int j, int a,
                                        float& x1, float& y1, float& x2, float& y2) {
    int am = a % 3, ad = a / 3;
    float h = 2.f * (float)(am + 1);              // 2,4,6
    float w = h * 0.5f * (float)(1 << ad);        // h*{0.5,1,2}
    float cx = (float)i + 0.5f, cy = (float)j + 0.5f;
    x1 = fminf(fmaxf(cx - 0.5f * w, 0.f), 62.f);
    x2 = fminf(fmaxf(cx + 0.5f * w, 0.f), 62.f);
    y1 = fminf(fmaxf(cy - 0.5f * h, 0.f), 62.f);
    y2 = fminf(fmaxf(cy + 0.5f * h, 0.f), 62.f);
}

__device__ __forceinline__ float iou_fn(float ax1, float ay1, float ax2, float ay2,
                                        float gx1, float gy1, float gx2, float gy2) {
    float area_a = __fmul_rn(__fsub_rn(ax2, ax1), __fsub_rn(ay2, ay1));
    float area_g = __fmul_rn(__fsub_rn(gx2, gx1), __fsub_rn(gy2, gy1));
    float ix1 = fmaxf(ax1, gx1), iy1 = fmaxf(ay1, gy1);
    float ix2 = fminf(ax2, gx2), iy2 = fminf(ay2, gy2);
    float iw = fmaxf(__fsub_rn(ix2, ix1), 0.f);
    float ih = fmaxf(__fsub_rn(iy2, iy1), 0.f);
    float inter = __fmul_rn(iw, ih);
    float uni = __fsub_rn(__fadd_rn(area_a, area_g), inter);
    return inter / fmaxf(uni, 1e-9f);
}

__device__ __forceinline__ float softplus_f(float x) {
    return fmaxf(x, 0.f) + log1pf(expf(-fabsf(x)));
}

__device__ __forceinline__ float sl1_f(float d) {
    float ad = fabsf(d);
    return (ad < 1.f) ? 0.5f * d * d : (ad - 0.5f);
}

// ---------- Kernel 1: prep (Bfrag fold | gt max-iou | effb + counter) ----------
// blocks [0,432): Bfrag elements (direct K=256 dot, no partial round-trip)
// blocks [432,560): per-(b,gt) max IoU; block 560: effb + counter zero
__global__ void prep1(const float* __restrict__ conv_w,
                      const float* __restrict__ conv_b,
                      const float* __restrict__ cls_w,
                      const float* __restrict__ cls_b,
                      const float* __restrict__ box_w,
                      const float* __restrict__ box_b,
                      const float* __restrict__ gtb,
                      unsigned short* __restrict__ Bfrag,
                      float* __restrict__ effb,
                      float* __restrict__ maxiou,
                      unsigned int* __restrict__ counter) {
    __shared__ float red[256];
    int blk = blockIdx.x, t = threadIdx.x;
    if (blk < 432) {
        int i = blk * 256 + t;               // < 110592 = 48*2304
        int o = i / 2304, idx = i - o * 2304;
        float s = 0.f;
        if (o < NOUT) {
            const float* w2 = (o < 9) ? (cls_w + o * FEATC) : (box_w + (o - 9) * FEATC);
#pragma unroll 8
            for (int m = 0; m < FEATC; ++m)
                s = fmaf(w2[m], conv_w[(size_t)m * 2304 + idx], s);  // w2 uniform, conv_w coalesced
        }
        int c = idx / 9, tap = idx - c * 9;
        int cc = c >> 6, kk = (c >> 5) & 1, lh = (c >> 3) & 3, j = c & 7;
        int lane = (lh << 4) | (o & 15), nf = o >> 4;
        Bfrag[((size_t)((((cc * 9 + tap) * 2 + kk) * 3 + nf) * 64 + lane)) * 8 + j] = f2bf(s);
    } else if (blk < 560) {
        int bg = blk - 432;
        int b = bg >> 3, g = bg & 7;
        const float* p = gtb + (b * NGT + g) * 4;
        float gx1 = p[0] * 0.125f, gy1 = p[1] * 0.125f;
        float gx2 = p[2] * 0.125f, gy2 = p[3] * 0.125f;
        float m = 0.f;
        for (int n = t; n < NANCH; n += 256) {
            int i = n / 558; int r = n - i * 558; int j = r / 9; int a = r - j * 9;
            float ax1, ay1, ax2, ay2;
            anchor4(i, j, a, ax1, ay1, ax2, ay2);
            m = fmaxf(m, iou_fn(ax1, ay1, ax2, ay2, gx1, gy1, gx2, gy2));
        }
        red[t] = m;
        __syncthreads();
        for (int s = 128; s > 0; s >>= 1) {
            if (t < s) red[t] = fmaxf(red[t], red[t + s]);
            __syncthreads();
        }
        if (t == 0) maxiou[bg] = red[0];
    } else {
        if (t == 0) *counter = 0u;
        if (t < 48) {
            float bv = 0.f;
            if (t < NOUT) {
                bv = (t < 9) ? cls_b[t] : box_b[t - 9];
                const float* w2 = (t < 9) ? (cls_w + t * FEATC) : (box_w + (t - 9) * FEATC);
                for (int mid = 0; mid < FEATC; ++mid) bv = fmaf(w2[mid], conv_b[mid], bv);
            }
            effb[t] = bv;
        }
    }
}

// ---------- Kernel 2: MFMA conv + fused epilogue + fused finalize ----------
// grid = (32 spatial tiles [8 tY x 4 tX], 16 batch), block = 512 (8 waves)
// wave w owns output row w of the 8x16 tile: 1 m-frag x 3 n-frags.
// R2-proven schedule: double-buffered LDS A, one barrier per K-chunk.
__launch_bounds__(512, 4)
__global__ void conv_fused(const float* __restrict__ feat,
                           const unsigned short* __restrict__ Bfrag,
                           const float* __restrict__ effb,
                           const float* __restrict__ gtb,
                           const int* __restrict__ gtc,
                           const float* __restrict__ maxiou,
                           float* __restrict__ outp,
                           float* __restrict__ blksums,
                           unsigned int* __restrict__ counter) {
    __shared__ __align__(16) unsigned char smem[2][23040];  // A dbuf; Cs overlays after K-loop
    __shared__ float gshr[40];
    __shared__ float red[512];
    __shared__ float tot[5];
    __shared__ unsigned int lastflag;

    float (*Cs)[49] = (float (*)[49])&smem[0][0];   // 128*49*4 = 25088 <= 46080

    const int t = threadIdx.x, l = t & 63, w = t >> 6;
    const int bx = blockIdx.x, b = blockIdx.y;
    const int tY = bx >> 2, tX = bx & 3;
    const int l15 = l & 15, lq = l >> 4;

    if (t < 32) gshr[t] = gtb[b * 32 + t] * 0.125f;
    else if (t < 40) gshr[t] = maxiou[b * 8 + (t - 32)];

    // accumulators init = folded bias
    f32x4 acc[3];
#pragma unroll
    for (int nf = 0; nf < 3; ++nf) {
        float bv = effb[nf * 16 + l15];
#pragma unroll
        for (int r = 0; r < 4; ++r) acc[nf][r] = bv;
    }

    float vr[3][8];  // staging regs: 3 (pix,ch-group) units per thread

    auto stage_load = [&](int cc) {
#pragma unroll
        for (int q = 0; q < 3; ++q) {
            int u = q * 512 + t;                // < 1440 = 180 pix * 8 ch-groups
            int pix = u >> 3, cg = u & 7;
            int iy = pix / 18, ix = pix - iy * 18;
            int gy = tY * 8 + iy, gx = tX * 16 + ix;
            bool ok = (u < 1440) && (gy < 64) && (gx < 64);
            const float* src = feat + (((size_t)b * FEATC + cc * 64 + cg * 8) * 64 + gy) * 64 + gx;
#pragma unroll
            for (int k = 0; k < 8; ++k)
                vr[q][k] = ok ? src[(size_t)k * 4096] : 0.f;
        }
    };
    auto stage_write = [&](int bb) {
        char* base = (char*)&smem[bb][0];
#pragma unroll
        for (int q = 0; q < 3; ++q) {
            int u = q * 512 + t;
            int pix = u >> 3, cg = u & 7;
            if (u < 1440) {
                bf16x8 v;
#pragma unroll
                for (int k = 0; k < 8; ++k) v[k] = (short)f2bf(vr[q][k]);
                int byte = (pix * 128 + cg * 16) ^ ((pix & 7) << 4);
                *reinterpret_cast<bf16x8*>(base + byte) = v;
            }
        }
    };
    auto compute = [&](int cc, int bb) {
        const bf16x8* Bp = reinterpret_cast<const bf16x8*>(Bfrag);
        const char* base = (const char*)&smem[bb][0];
#pragma unroll
        for (int dy = 0; dy < 3; ++dy)
#pragma unroll
            for (int dx = 0; dx < 3; ++dx)
#pragma unroll
                for (int kk = 0; kk < 2; ++kk) {
                    int tap = dy * 3 + dx;
                    bf16x8 bfr[3];
#pragma unroll
                    for (int nf = 0; nf < 3; ++nf)
                        bfr[nf] = Bp[(((cc * 9 + tap) * 2 + kk) * 3 + nf) * 64 + l];
                    int pix = (w + dy) * 18 + l15 + dx;
                    int byte = (pix * 128 + kk * 64 + (lq << 4)) ^ ((pix & 7) << 4);
                    bf16x8 afr = *reinterpret_cast<const bf16x8*>(base + byte);
#pragma unroll
                    for (int nf = 0; nf < 3; ++nf)
                        acc[nf] = __builtin_amdgcn_mfma_f32_16x16x32_bf16(
                            afr, bfr[nf], acc[nf], 0, 0, 0);
                }
    };

    // K-loop, double-buffered, one barrier per chunk (R2-proven)
    stage_load(0);
    stage_write(0);
    __syncthreads();
    for (int cc = 0; cc < 4; ++cc) {
        if (cc < 3) stage_load(cc + 1);          // loads in flight during MFMA
        compute(cc, cc & 1);
        if (cc < 3) stage_write((cc + 1) & 1);   // other buffer: no hazard with readers of cc&1
        __syncthreads();
    }

    // C fragments -> LDS (Cs overlays A region; safe after final sync)
#pragma unroll
    for (int nf = 0; nf < 3; ++nf)
#pragma unroll
        for (int r = 0; r < 4; ++r) {
            int px = (lq << 2) + r;
            Cs[(w << 4) + px][nf * 16 + l15] = acc[nf][r];
        }
    __syncthreads();

    // ---- fused per-anchor epilogue: 8x16 pixels x 9 anchors = 1152 anchors ----
    float s_pos = 0.f, s_neg = 0.f, s_pl = 0.f, s_nl = 0.f, s_reg = 0.f;
    float* out_prop = outp + 2;
    float* out_mask = out_prop + (size_t)NBAT * NANCH * 4;
    float* out_gtc  = out_mask + (size_t)NBAT * NANCH * 8;

    for (int k = 0; k < 3; ++k) {
        int an = k * 512 + t;
        if (an < 1152) {
            int pixloc = an / 9, a = an - pixloc * 9;
            int py = pixloc >> 4, px = pixloc & 15;
            int oy = tY * 8 + py, ox = tX * 16 + px;
            if (oy < HW2 && ox < HW2) {
                int n = oy * 558 + ox * 9 + a;
                float cls = Cs[pixloc][a];
                float p0 = Cs[pixloc][9 + 4 * a];
                float p1 = Cs[pixloc][10 + 4 * a];
                float p2 = Cs[pixloc][11 + 4 * a];
                float p3 = Cs[pixloc][12 + 4 * a];

                float ax1, ay1, ax2, ay2;
                anchor4(oy, ox, a, ax1, ay1, ax2, ay2);
                float aw = ax2 - ax1, ah = ay2 - ay1;
                float acx = 0.5f * (ax1 + ax2), acy = 0.5f * (ay1 + ay2);

                const float ps = 64.f / 62.f;
                float pcx = acx + p0 * aw, pcy = acy + p1 * ah;
                float pw = aw * expf(p2), ph = ah * expf(p3);
                size_t pb = ((size_t)b * NANCH + n) * 4;
                out_prop[pb + 0] = (pcx - 0.5f * pw) * ps;
                out_prop[pb + 1] = (pcy - 0.5f * ph) * ps;
                out_prop[pb + 2] = (pcx + 0.5f * pw) * ps;
                out_prop[pb + 3] = (pcy + 0.5f * ph) * ps;

                float law = logf(aw), lah = logf(ah);
                float posf_tot = 0.f, negf_tot = 0.f;
                float best_iou = -1.f; int best_g = 0;
                size_t mb = ((size_t)b * NANCH + n) * 8;
#pragma unroll
                for (int g = 0; g < NGT; ++g) {
                    float gx1 = gshr[g * 4 + 0], gy1 = gshr[g * 4 + 1];
                    float gx2 = gshr[g * 4 + 2], gy2 = gshr[g * 4 + 3];
                    float iou = iou_fn(ax1, ay1, ax2, ay2, gx1, gy1, gx2, gy2);
                    float mpg = gshr[32 + g];
                    bool pm = ((iou == mpg) && (mpg > 0.f)) || (iou > 0.7f);
                    float pf = pm ? 1.f : 0.f;
                    float nf = (iou < 0.3f) ? 1.f : 0.f;
                    out_mask[mb + g] = pf;
                    posf_tot += pf; negf_tot += nf;
                    if (iou > best_iou) { best_iou = iou; best_g = g; }  // first-max-wins
                    if (pm) {
                        float gw = gx2 - gx1, gh = gy2 - gy1;
                        float gcx = 0.5f * (gx1 + gx2), gcy = 0.5f * (gy1 + gy2);
                        float tx_ = (gcx - acx) / aw, ty_ = (gcy - acy) / ah;
                        float tw_ = logf(gw) - law, th_ = logf(gh) - lah;
                        float d0 = p0 - tx_, d1 = p1 - ty_, d2 = p2 - tw_, d3 = p3 - th_;
                        s_reg += sl1_f(d0) + sl1_f(d1) + sl1_f(d2) + sl1_f(d3);
                    }
                }
                s_pos += posf_tot; s_neg += negf_tot;
                s_pl += softplus_f(-cls) * posf_tot;
                s_nl += softplus_f(cls) * negf_tot;
                out_gtc[(size_t)b * NANCH + n] = (float)gtc[b * NGT + best_g];
            }
        }
    }

    // deterministic per-block tree reduction of the 5 loss partials
    int blk = b * 32 + bx;   // nblk = 512
    float vals[5] = {s_pos, s_neg, s_pl, s_nl, s_reg};
#pragma unroll
    for (int s = 0; s < 5; ++s) {
        red[t] = vals[s];
        __syncthreads();
        for (int st = 256; st > 0; st >>= 1) {
            if (t < st) red[t] += red[t + st];
            __syncthreads();
        }
        if (t == 0) blksums[(size_t)s * 512 + blk] = red[0];
        __syncthreads();
    }

    // fused finalize: last block (fence+atomic) does the fixed-order reduce
    if (t == 0) {
        __threadfence();
        lastflag = (atomicAdd(counter, 1u) == 511u) ? 1u : 0u;
    }
    __syncthreads();
    if (lastflag) {
        __threadfence();
#pragma unroll
        for (int s = 0; s < 5; ++s) {
            float a = (t < 512) ? blksums[(size_t)s * 512 + t] : 0.f;
            red[t] = a;
            __syncthreads();
            for (int st = 256; st > 0; st >>= 1) {
                if (t < st) red[t] += red[t + st];
                __syncthreads();
            }
            if (t == 0) tot[s] = red[0];
            __syncthreads();
        }
        if (t == 0) {
            float np_ = fmaxf(tot[0], 1.f), nn_ = fmaxf(tot[1], 1.f);
            outp[0] = 0.5f * (tot[2] / np_ + tot[3] / nn_);  // cls_loss
            outp[1] = tot[4] / (np_ * 4.f);                  // reg_loss
        }
    }
}

extern "C" void kernel_launch(void* const* d_in, const int* in_sizes, int n_in,
                              void* d_out, int out_size, void* d_ws, size_t ws_size,
                              hipStream_t stream) {
    (void)in_sizes; (void)n_in; (void)out_size; (void)ws_size;
    const float* feat   = (const float*)d_in[0];
    const float* gtb    = (const float*)d_in[1];
    const int*   gtc    = (const int*)d_in[2];
    const float* conv_w = (const float*)d_in[3];
    const float* conv_b = (const float*)d_in[4];
    const float* cls_w  = (const float*)d_in[5];
    const float* cls_b  = (const float*)d_in[6];
    const float* box_w  = (const float*)d_in[7];
    const float* box_b  = (const float*)d_in[8];
    float* outp = (float*)d_out;
    float* ws   = (float*)d_ws;

    // workspace layout (floats), ~232 KB total
    unsigned short* Bfrag   = (unsigned short*)ws;            // 110592 ushorts = 55296 fl
    float*          effb    = ws + 55296;                     // 48 (pad 64)
    float*          maxiou  = ws + 55360;                     // 128
    unsigned int*   counter = (unsigned int*)(ws + 55488);    // 1 (pad 64)
    float*          blksums = ws + 55552;                     // 5*512

    prep1<<<561, 256, 0, stream>>>(conv_w, conv_b, cls_w, cls_b, box_w, box_b, gtb,
                                   Bfrag, effb, maxiou, counter);
    conv_fused<<<dim3(32, NBAT), 512, 0, stream>>>(feat, Bfrag, effb, gtb, gtc, maxiou,
                                                   outp, blksums, counter);
}

// Round 5
// 107.878 us; speedup vs baseline: 1.5747x; 1.0951x over previous
//
#include <hip/hip_runtime.h>
#include <math.h>

#define HW2   62
#define NANCH 34596   // 62*62*9
#define NBAT  16
#define NGT   8
#define FEATC 256
#define NOUT  45      // 9 cls + 36 box channels

typedef short bf16x8 __attribute__((ext_vector_type(8)));
typedef float f32x4  __attribute__((ext_vector_type(4)));

// fp32 -> bf16 round-to-nearest-even
__device__ __forceinline__ unsigned short f2bf(float f) {
    unsigned int u = __float_as_uint(f);
    u = u + 0x7FFFu + ((u >> 16) & 1u);
    return (unsigned short)(u >> 16);
}

// ---------- shared device helpers (bitwise identical to passing R2-R4) ----------

__device__ __forceinline__ void anchor4(int i, int j, int a,
                                        float& x1, float& y1, float& x2, float& y2) {
    int am = a % 3, ad = a / 3;
    float h = 2.f * (float)(am + 1);              // 2,4,6
    float w = h * 0.5f * (float)(1 << ad);        // h*{0.5,1,2}
    float cx = (float)i + 0.5f, cy = (float)j + 0.5f;
    x1 = fminf(fmaxf(cx - 0.5f * w, 0.f), 62.f);
    x2 = fminf(fmaxf(cx + 0.5f * w, 0.f), 62.f);
    y1 = fminf(fmaxf(cy - 0.5f * h, 0.f), 62.f);
    y2 = fminf(fmaxf(cy + 0.5f * h, 0.f), 62.f);
}

__device__ __forceinline__ float iou_fn(float ax1, float ay1, float ax2, float ay2,
                                        float gx1, float gy1, float gx2, float gy2) {
    float area_a = __fmul_rn(__fsub_rn(ax2, ax1), __fsub_rn(ay2, ay1));
    float area_g = __fmul_rn(__fsub_rn(gx2, gx1), __fsub_rn(gy2, gy1));
    float ix1 = fmaxf(ax1, gx1), iy1 = fmaxf(ay1, gy1);
    float ix2 = fminf(ax2, gx2), iy2 = fminf(ay2, gy2);
    float iw = fmaxf(__fsub_rn(ix2, ix1), 0.f);
    float ih = fmaxf(__fsub_rn(iy2, iy1), 0.f);
    float inter = __fmul_rn(iw, ih);
    float uni = __fsub_rn(__fadd_rn(area_a, area_g), inter);
    return inter / fmaxf(uni, 1e-9f);
}

__device__ __forceinline__ float softplus_f(float x) {
    return fmaxf(x, 0.f) + log1pf(expf(-fabsf(x)));
}

__device__ __forceinline__ float sl1_f(float d) {
    float ad = fabsf(d);
    return (ad < 1.f) ? 0.5f * d * d : (ad - 0.5f);
}

// ---------- Kernel 1: fold partials (R2-proven), zero counter ----------
// grid (9, 4): 256 idx per block, 64 mids per group
// partial[(g*45+o)*2304 + idx]
__global__ void fold_part(const float* __restrict__ conv_w,
                          const float* __restrict__ cls_w,
                          const float* __restrict__ box_w,
                          float* __restrict__ partial,
                          unsigned int* __restrict__ counter) {
    if (blockIdx.x == 0 && blockIdx.y == 0 && threadIdx.x == 0) *counter = 0u;
    __shared__ float w2s[64][45];
    int g = blockIdx.y, t = threadIdx.x;
    for (int i = t; i < 64 * 45; i += 256) {
        int m = i / 45, o = i - m * 45;
        w2s[m][o] = (o < 9) ? cls_w[o * FEATC + g * 64 + m]
                            : box_w[(o - 9) * FEATC + g * 64 + m];
    }
    __syncthreads();
    int idx = blockIdx.x * 256 + t;
    float acc[NOUT];
#pragma unroll
    for (int o = 0; o < NOUT; ++o) acc[o] = 0.f;
    for (int m = 0; m < 64; ++m) {
        float cw = conv_w[(size_t)(g * 64 + m) * 2304 + idx];   // coalesced
#pragma unroll
        for (int o = 0; o < NOUT; ++o)
            acc[o] = fmaf(cw, w2s[m][o], acc[o]);
    }
#pragma unroll
    for (int o = 0; o < NOUT; ++o)
        partial[(size_t)(g * NOUT + o) * 2304 + idx] = acc[o];
}

// ---------- Kernel 2: combine -> Bfrag (chunk-major) | gt max-iou | effb ----------
// Bfrag layout: [cc2=c>>5][tap][nf][lane][j]  (per-cc2 block 27648 B contiguous)
__global__ void prep2(const float* __restrict__ partial,
                      const float* __restrict__ conv_b,
                      const float* __restrict__ cls_b,
                      const float* __restrict__ box_b,
                      const float* __restrict__ cls_w,
                      const float* __restrict__ box_w,
                      const float* __restrict__ gtb,
                      unsigned short* __restrict__ Bfrag,
                      float* __restrict__ effb,
                      float* __restrict__ maxiou) {
    __shared__ float red[256];
    int blk = blockIdx.x, t = threadIdx.x;
    if (blk < 432) {
        int i = blk * 256 + t;               // < 110592 = 48*2304
        int o = i / 2304, idx = i - o * 2304;
        float s = 0.f;
        if (o < NOUT) {
#pragma unroll
            for (int g = 0; g < 4; ++g)
                s += partial[(size_t)(g * NOUT + o) * 2304 + idx];
        }
        int c = idx / 9, tap = idx - c * 9;
        size_t slot = (((size_t)(c >> 5) * 9 + tap) * 3 + (o >> 4)) * 512
                    + (size_t)((((c >> 3) & 3) * 16) + (o & 15)) * 8 + (c & 7);
        Bfrag[slot] = f2bf(s);
    } else if (blk < 560) {
        int bg = blk - 432;
        int b = bg >> 3, g = bg & 7;
        const float* p = gtb + (b * NGT + g) * 4;
        float gx1 = p[0] * 0.125f, gy1 = p[1] * 0.125f;
        float gx2 = p[2] * 0.125f, gy2 = p[3] * 0.125f;
        float m = 0.f;
        for (int n = t; n < NANCH; n += 256) {
            int i = n / 558; int r = n - i * 558; int j = r / 9; int a = r - j * 9;
            float ax1, ay1, ax2, ay2;
            anchor4(i, j, a, ax1, ay1, ax2, ay2);
            m = fmaxf(m, iou_fn(ax1, ay1, ax2, ay2, gx1, gy1, gx2, gy2));
        }
        red[t] = m;
        __syncthreads();
        for (int s = 128; s > 0; s >>= 1) {
            if (t < s) red[t] = fmaxf(red[t], red[t + s]);
            __syncthreads();
        }
        if (t == 0) maxiou[bg] = red[0];
    } else {
        if (t < 48) {
            float bv = 0.f;
            if (t < NOUT) {
                bv = (t < 9) ? cls_b[t] : box_b[t - 9];
                const float* w2 = (t < 9) ? (cls_w + t * FEATC) : (box_w + (t - 9) * FEATC);
                for (int mid = 0; mid < FEATC; ++mid) bv = fmaf(w2[mid], conv_b[mid], bv);
            }
            effb[t] = bv;
        }
    }
}

// ---------- Kernel 3: features fp32 NCHW -> bf16 chunk-major [b][cc][y][x][32c] ----------
// grid (32 y-pairs, 8 cc, g batch), 256 threads
__global__ void to_bf16(const float* __restrict__ feat,
                        unsigned short* __restrict__ ft, int b_base) {
    __shared__ float ldsT[32 * 2 * 64];   // [ch][y][x], x XOR-swizzled by ch
    int yp = blockIdx.x, cc = blockIdx.y, bz = blockIdx.z;
    int b = b_base + bz;
    int y0 = yp * 2, t = threadIdx.x;
#pragma unroll
    for (int k = 0; k < 4; ++k) {
        int fi = k * 256 + t;
        int ch = fi >> 5, r = fi & 31;
        int y = r >> 4, xq = r & 15;
        f32x4 v = *(const f32x4*)(feat + ((size_t)(b * 256 + cc * 32 + ch) << 12)
                                  + (y0 + y) * 64 + xq * 4);
        int word = ch * 128 + y * 64 + ((xq * 4) ^ ((ch & 7) << 3));
        *(f32x4*)(ldsT + word) = v;
    }
    __syncthreads();
    int y = t >> 7, x = (t >> 1) & 63, h2 = t & 1;
    bf16x8 o0, o1;
#pragma unroll
    for (int j = 0; j < 8; ++j) {
        int ch = h2 * 16 + j;
        o0[j] = (short)f2bf(ldsT[ch * 128 + y * 64 + (x ^ ((ch & 7) << 3))]);
    }
#pragma unroll
    for (int j = 0; j < 8; ++j) {
        int ch = h2 * 16 + 8 + j;
        o1[j] = (short)f2bf(ldsT[ch * 128 + y * 64 + (x ^ ((ch & 7) << 3))]);
    }
    unsigned short* dst = ft + ((size_t)(bz * 8 + cc) << 17)
                        + ((size_t)((y0 + y) * 64 + x)) * 32 + h2 * 16;
    *(bf16x8*)dst = o0;
    *(bf16x8*)(dst + 8) = o1;
}

// ---------- Kernel 4: MFMA conv (A+B both LDS-staged) + fused epilogue/finalize ----------
// grid (16 bands of 4 rows, g batch), 512 threads (8 waves).
// Wave w: 2 m-frags (pixels w*32+{0..31}) x 3 n-frags. K-chunks: 8 x 32ch, dbuf, 1 barrier.
__launch_bounds__(512, 2)
__global__ void conv_fused(const unsigned short* __restrict__ ft,
                           const unsigned short* __restrict__ Bfrag,
                           const float* __restrict__ effb,
                           const float* __restrict__ gtb,
                           const int* __restrict__ gtc,
                           const float* __restrict__ maxiou,
                           float* __restrict__ outp,
                           float* __restrict__ blksums,
                           unsigned int* __restrict__ counter,
                           int b_base) {
    __shared__ __align__(16) unsigned char smem[104448]; // A dbuf 2x24576 | B dbuf 2x27648; Cs overlays
    __shared__ float gshr[40];
    __shared__ float red[512];
    __shared__ float tot[5];
    __shared__ unsigned int lastflag;

    const int t = threadIdx.x, l = t & 63, w = t >> 6;
    const int band = blockIdx.x;
    const int bz = blockIdx.y, b = b_base + bz;
    const int l15 = l & 15, lq = l >> 4;
    const int y0 = band * 4;

    if (t < 32) gshr[t] = gtb[b * 32 + t] * 0.125f;
    else if (t < 40) gshr[t] = maxiou[b * 8 + (t - 32)];

    f32x4 acc[2][3];
#pragma unroll
    for (int nf = 0; nf < 3; ++nf) {
        float bv = effb[nf * 16 + l15];
#pragma unroll
        for (int mf = 0; mf < 2; ++mf)
#pragma unroll
            for (int r = 0; r < 4; ++r) acc[mf][nf][r] = bv;
    }

    // per-thread A read bases (pixel -> (row,col) in the 4x62 band, clamped)
    int p0 = w * 32 + l15;      p0 = (p0 > 247) ? 247 : p0;
    int p1 = w * 32 + 16 + l15; p1 = (p1 > 247) ? 247 : p1;
    int rr0 = p0 / 62, c0 = p0 - rr0 * 62;
    int rr1 = p1 / 62, c1 = p1 - rr1 * 62;
    int ab0 = rr0 * 4096 + c0 * 64 + lq * 16;
    int ab1 = rr1 * 4096 + c1 * 64 + lq * 16;

    bf16x8 vA[3], vB[4];

    auto loadA = [&](int cc) {
        const unsigned short* At = ft + ((size_t)(bz * 8 + cc) << 17);
#pragma unroll
        for (int k = 0; k < 3; ++k) {
            int u = t + k * 512;               // < 1536 units of 16B (6 rows x 256)
            int r = u >> 8;
            int gy = y0 + r; if (gy > 63) gy = 63;   // band 15 clamp
            vA[k] = *(const bf16x8*)(At + (size_t)gy * 2048 + (u & 255) * 8);
        }
    };
    auto loadB = [&](int cc) {
        const unsigned short* Bt = Bfrag + cc * 13824;
#pragma unroll
        for (int k = 0; k < 4; ++k) {
            int u = t + k * 512;               // < 1728 units
            if (u < 1728) vB[k] = *(const bf16x8*)(Bt + u * 8);
        }
    };
    auto writeA = [&](int bb) {
        char* p = (char*)smem + bb * 24576;
#pragma unroll
        for (int k = 0; k < 3; ++k) *(bf16x8*)(p + (t + k * 512) * 16) = vA[k];
    };
    auto writeB = [&](int bb) {
        char* p = (char*)smem + 49152 + bb * 27648;
#pragma unroll
        for (int k = 0; k < 4; ++k) {
            int u = t + k * 512;
            if (u < 1728) *(bf16x8*)(p + u * 16) = vB[k];
        }
    };
    auto compute = [&](int bb) {
        const char* Ab = (const char*)smem + bb * 24576;
        const char* Bb = (const char*)smem + 49152 + bb * 27648;
#pragma unroll
        for (int dy = 0; dy < 3; ++dy)
#pragma unroll
            for (int dx = 0; dx < 3; ++dx) {
                int tap = dy * 3 + dx;
                bf16x8 bfr[3];
#pragma unroll
                for (int nf = 0; nf < 3; ++nf)
                    bfr[nf] = *(const bf16x8*)(Bb + ((tap * 3 + nf) * 64 + l) * 16);
                bf16x8 a0 = *(const bf16x8*)(Ab + ab0 + dy * 4096 + dx * 64);
                bf16x8 a1 = *(const bf16x8*)(Ab + ab1 + dy * 4096 + dx * 64);
#pragma unroll
                for (int nf = 0; nf < 3; ++nf) {
                    acc[0][nf] = __builtin_amdgcn_mfma_f32_16x16x32_bf16(a0, bfr[nf], acc[0][nf], 0, 0, 0);
                    acc[1][nf] = __builtin_amdgcn_mfma_f32_16x16x32_bf16(a1, bfr[nf], acc[1][nf], 0, 0, 0);
                }
            }
    };

    // K-loop: double-buffered A+B, loads issued before compute, 1 barrier/chunk
    loadA(0); loadB(0);
    writeA(0); writeB(0);
    __syncthreads();
    for (int cc = 0; cc < 8; ++cc) {
        if (cc < 7) { loadA(cc + 1); loadB(cc + 1); }
        compute(cc & 1);
        if (cc < 7) { writeA((cc + 1) & 1); writeB((cc + 1) & 1); }
        __syncthreads();
    }

    // C fragments -> LDS (overlays staging buffers)
    float (*Cs)[49] = (float (*)[49])smem;    // 248 x 49 x 4B = 48.6 KB
#pragma unroll
    for (int mf = 0; mf < 2; ++mf)
#pragma unroll
        for (int nf = 0; nf < 3; ++nf)
#pragma unroll
            for (int r = 0; r < 4; ++r) {
                int pix = w * 32 + mf * 16 + lq * 4 + r;
                if (pix < 248) Cs[pix][nf * 16 + l15] = acc[mf][nf][r];
            }
    __syncthreads();

    // ---- fused per-anchor epilogue: 4x62 pixels x 9 anchors = 2232 anchors ----
    float s_pos = 0.f, s_neg = 0.f, s_pl = 0.f, s_nl = 0.f, s_reg = 0.f;
    float* out_prop = outp + 2;
    float* out_mask = out_prop + (size_t)NBAT * NANCH * 4;
    float* out_gtc  = out_mask + (size_t)NBAT * NANCH * 8;

    for (int k = 0; k < 5; ++k) {
        int an = k * 512 + t;
        if (an < 2232) {
            int pixloc = an / 9, a = an - pixloc * 9;
            int rr = pixloc / 62, col = pixloc - rr * 62;
            int oy = y0 + rr, ox = col;
            if (oy < HW2) {
                int n = oy * 558 + ox * 9 + a;
                float cls = Cs[pixloc][a];
                float p0f = Cs[pixloc][9 + 4 * a];
                float p1f = Cs[pixloc][10 + 4 * a];
                float p2f = Cs[pixloc][11 + 4 * a];
                float p3f = Cs[pixloc][12 + 4 * a];

                float ax1, ay1, ax2, ay2;
                anchor4(oy, ox, a, ax1, ay1, ax2, ay2);
                float aw = ax2 - ax1, ah = ay2 - ay1;
                float acx = 0.5f * (ax1 + ax2), acy = 0.5f * (ay1 + ay2);

                const float ps = 64.f / 62.f;
                float pcx = acx + p0f * aw, pcy = acy + p1f * ah;
                float pw = aw * expf(p2f), ph = ah * expf(p3f);
                size_t pb = ((size_t)b * NANCH + n) * 4;
                out_prop[pb + 0] = (pcx - 0.5f * pw) * ps;
                out_prop[pb + 1] = (pcy - 0.5f * ph) * ps;
                out_prop[pb + 2] = (pcx + 0.5f * pw) * ps;
                out_prop[pb + 3] = (pcy + 0.5f * ph) * ps;

                float law = logf(aw), lah = logf(ah);
                float posf_tot = 0.f, negf_tot = 0.f;
                float best_iou = -1.f; int best_g = 0;
                size_t mb = ((size_t)b * NANCH + n) * 8;
#pragma unroll
                for (int g = 0; g < NGT; ++g) {
                    float gx1 = gshr[g * 4 + 0], gy1 = gshr[g * 4 + 1];
                    float gx2 = gshr[g * 4 + 2], gy2 = gshr[g * 4 + 3];
                    float iou = iou_fn(ax1, ay1, ax2, ay2, gx1, gy1, gx2, gy2);
                    float mpg = gshr[32 + g];
                    bool pm = ((iou == mpg) && (mpg > 0.f)) || (iou > 0.7f);
                    float pf = pm ? 1.f : 0.f;
                    float nf = (iou < 0.3f) ? 1.f : 0.f;
                    out_mask[mb + g] = pf;
                    posf_tot += pf; negf_tot += nf;
                    if (iou > best_iou) { best_iou = iou; best_g = g; }  // first-max-wins
                    if (pm) {
                        float gw = gx2 - gx1, gh = gy2 - gy1;
                        float gcx = 0.5f * (gx1 + gx2), gcy = 0.5f * (gy1 + gy2);
                        float tx_ = (gcx - acx) / aw, ty_ = (gcy - acy) / ah;
                        float tw_ = logf(gw) - law, th_ = logf(gh) - lah;
                        float d0 = p0f - tx_, d1 = p1f - ty_, d2 = p2f - tw_, d3 = p3f - th_;
                        s_reg += sl1_f(d0) + sl1_f(d1) + sl1_f(d2) + sl1_f(d3);
                    }
                }
                s_pos += posf_tot; s_neg += negf_tot;
                s_pl += softplus_f(-cls) * posf_tot;
                s_nl += softplus_f(cls) * negf_tot;
                out_gtc[(size_t)b * NANCH + n] = (float)gtc[b * NGT + best_g];
            }
        }
    }

    // deterministic per-block tree reduction of the 5 loss partials
    int blk = b * 16 + band;   // nblk = 256
    float vals[5] = {s_pos, s_neg, s_pl, s_nl, s_reg};
#pragma unroll
    for (int s = 0; s < 5; ++s) {
        red[t] = vals[s];
        __syncthreads();
        for (int st = 256; st > 0; st >>= 1) {
            if (t < st) red[t] += red[t + st];
            __syncthreads();
        }
        if (t == 0) blksums[(size_t)s * 256 + blk] = red[0];
        __syncthreads();
    }

    // fused finalize: last block (fence+atomic) does the fixed-order reduce
    if (t == 0) {
        __threadfence();
        lastflag = (atomicAdd(counter, 1u) == 255u) ? 1u : 0u;
    }
    __syncthreads();
    if (lastflag) {
        __threadfence();
#pragma unroll
        for (int s = 0; s < 5; ++s) {
            red[t] = (t < 256) ? blksums[(size_t)s * 256 + t] : 0.f;
            __syncthreads();
            for (int st = 256; st > 0; st >>= 1) {
                if (t < st) red[t] += red[t + st];
                __syncthreads();
            }
            if (t == 0) tot[s] = red[0];
            __syncthreads();
        }
        if (t == 0) {
            float np_ = fmaxf(tot[0], 1.f), nn_ = fmaxf(tot[1], 1.f);
            outp[0] = 0.5f * (tot[2] / np_ + tot[3] / nn_);  // cls_loss
            outp[1] = tot[4] / (np_ * 4.f);                  // reg_loss
        }
    }
}

extern "C" void kernel_launch(void* const* d_in, const int* in_sizes, int n_in,
                              void* d_out, int out_size, void* d_ws, size_t ws_size,
                              hipStream_t stream) {
    (void)in_sizes; (void)n_in; (void)out_size;
    const float* feat   = (const float*)d_in[0];
    const float* gtb    = (const float*)d_in[1];
    const int*   gtc    = (const int*)d_in[2];
    const float* conv_w = (const float*)d_in[3];
    const float* conv_b = (const float*)d_in[4];
    const float* cls_w  = (const float*)d_in[5];
    const float* cls_b  = (const float*)d_in[6];
    const float* box_w  = (const float*)d_in[7];
    const float* box_b  = (const float*)d_in[8];
    float* outp = (float*)d_out;
    float* ws   = (float*)d_ws;

    // workspace layout (floats)
    unsigned short* Bfrag   = (unsigned short*)ws;            // 110592 us = 55296 fl
    float*          effb    = ws + 55296;                     // 64
    float*          maxiou  = ws + 55360;                     // 128
    unsigned int*   counter = (unsigned int*)(ws + 55488);    // 64
    float*          blksums = ws + 55552;                     // 5*256 -> pad 1536
    float*          partial = ws + 57088;                     // 4*45*2304 = 414720
    unsigned short* ft      = (unsigned short*)(ws + 471808); // g * 1048576 ushorts

    // batch-group size: largest g in {16,8,4,2,1} that fits the workspace
    size_t avail = ws_size / 4;
    int g = 16;
    while (g > 1 && (size_t)471808 + (size_t)g * 524288 > avail) g >>= 1;

    fold_part<<<dim3(9, 4), 256, 0, stream>>>(conv_w, cls_w, box_w, partial, counter);
    prep2<<<561, 256, 0, stream>>>(partial, conv_b, cls_b, box_b, cls_w, box_w, gtb,
                                   Bfrag, effb, maxiou);
    for (int b0 = 0; b0 < NBAT; b0 += g) {
        to_bf16<<<dim3(32, 8, g), 256, 0, stream>>>(feat, ft, b0);
        conv_fused<<<dim3(16, g), 512, 0, stream>>>(ft, Bfrag, effb, gtb, gtc, maxiou,
                                                    outp, blksums, counter, b0);
    }
}